// Round 8
// baseline (797.902 us; speedup 1.0000x reference)
//
#include <hip/hip_runtime.h>

#define NN 50000
#define NE 800000
#define HD 128
#define NL 4
#define NC 10
#define NG 256
#define NB 391            // CSR buckets of 128 nodes

typedef __attribute__((ext_vector_type(8))) short short8;    // 8 bf16 = 4 VGPR (MFMA A/B frag)
typedef __attribute__((ext_vector_type(4))) float floatx4;   // MFMA C/D frag

union frg { uint4 u; short8 s; };

__device__ __forceinline__ short8 load_frag(const ushort* p){
  frg f; f.u = *(const uint4*)p; return f.s;
}
__device__ __forceinline__ floatx4 MFMA(short8 a, short8 b, floatx4 c){
  return __builtin_amdgcn_mfma_f32_16x16x32_bf16(a, b, c, 0, 0, 0);
}

__device__ __forceinline__ ushort f2bf(float x){           // RNE fp32->bf16
  unsigned u = __float_as_uint(x);
  return (ushort)((u + 0x7FFFu + ((u >> 16) & 1u)) >> 16);
}
__device__ __forceinline__ float bf2f(ushort b){
  return __uint_as_float(((uint)b) << 16);
}
__device__ __forceinline__ float sigmf(float x){ return 1.0f/(1.0f + __expf(-x)); }
__device__ __forceinline__ float tanhff(float x){ return 2.0f/(1.0f + __expf(-2.0f*x)) - 1.0f; }

// ---------------- prep: convert whh / local_w to bf16; fold biases ----------------
__global__ __launch_bounds__(256) void prep_weights_bf16(
    const float* __restrict__ w_hh, const float* __restrict__ local_w,
    const float* __restrict__ b_ih, const float* __restrict__ b_hh,
    ushort* __restrict__ whh_bf, ushort* __restrict__ lw_bf,
    float* __restrict__ bs)
{
  int idx = blockIdx.x*256 + threadIdx.x;
  if (idx < 49152) whh_bf[idx] = f2bf(w_hh[idx]);
  else if (idx < 65536){ int j = idx - 49152; lw_bf[j] = f2bf(local_w[j]); }
  else if (idx < 66048){
    int j = idx - 65536;       // 0..511: br(128), bz(128), bin(128), bhn(128)
    if (j < 256)      bs[j] = b_ih[j] + b_hh[j];
    else if (j < 384) bs[j] = b_ih[j];          // bin
    else              bs[j] = b_hh[j - 128];    // bhn
  }
}

// ---------------- Veff[l]^T[o][j] = sum_f W[l][j][f] * wih[o][f]  (fp32 acc -> bf16) ----------------
__global__ __launch_bounds__(256) void veff_kernel(
    const float* __restrict__ W, const float* __restrict__ w_ih,
    ushort* __restrict__ veffT)
{
  int idx = blockIdx.x*256 + threadIdx.x;    // l*49152 + o*128 + j
  if (idx >= 4*49152) return;
  int l = idx / 49152, rem = idx % 49152;
  int o = rem >> 7, j = rem & 127;
  const float4* wr = (const float4*)&W[(size_t)(l*128 + j)*128];
  const float4* ir = (const float4*)&w_ih[(size_t)o*128];
  float acc = 0.f;
  #pragma unroll
  for (int q = 0; q < 32; q++){
    float4 a = wr[q], b = ir[q];
    acc += a.x*b.x + a.y*b.y + a.z*b.z + a.w*b.w;
  }
  veffT[idx] = f2bf(acc);
}

__global__ __launch_bounds__(256) void convert_x(const float4* __restrict__ x, ushort4* __restrict__ xbf)
{
  int i = blockIdx.x*256 + threadIdx.x;
  if (i < NN*HD/4){
    float4 v = x[i];
    ushort4 o; o.x=f2bf(v.x); o.y=f2bf(v.y); o.z=f2bf(v.z); o.w=f2bf(v.w);
    xbf[i] = o;
  }
}

// ---------------- CSR build ----------------
__global__ __launch_bounds__(256) void count_deg(const int* __restrict__ dst, int* deg)
{
  int e = blockIdx.x*256 + threadIdx.x;
  if (e < NE){
    int d = __builtin_nontemporal_load(&dst[e]);
    atomicAdd(&deg[d], 1);
  }
}

__global__ __launch_bounds__(1024) void scan_blocks(
    const int* __restrict__ deg, int* __restrict__ excl_out, int* __restrict__ bsum)
{
  __shared__ int wsum[16];
  int t = threadIdx.x;
  int gid = blockIdx.x*1024 + t;
  int v = (gid < NN) ? deg[gid] : 0;
  int lane = t & 63, wv = t >> 6;
  int incl = v;
  #pragma unroll
  for (int off=1; off<64; off<<=1){
    int y = __shfl_up(incl, off, 64);
    if (lane >= off) incl += y;
  }
  if (lane == 63) wsum[wv] = incl;
  __syncthreads();
  if (wv == 0){
    int s = (lane < 16) ? wsum[lane] : 0;
    #pragma unroll
    for (int off=1; off<16; off<<=1){
      int y = __shfl_up(s, off, 64);
      if (lane >= off) s += y;
    }
    if (lane < 16) wsum[lane] = s;
  }
  __syncthreads();
  int wpre = (wv > 0) ? wsum[wv-1] : 0;
  if (gid < NN) excl_out[gid] = wpre + incl - v;
  if (t == 1023) bsum[blockIdx.x] = wpre + incl;
}

__global__ __launch_bounds__(64) void scan_carry(int* bsum, int* __restrict__ row_ptr)
{
  int lane = threadIdx.x;
  int v = (lane < 49) ? bsum[lane] : 0;
  int incl = v;
  #pragma unroll
  for (int off=1; off<64; off<<=1){
    int y = __shfl_up(incl, off, 64);
    if (lane >= off) incl += y;
  }
  if (lane < 49) bsum[lane] = incl - v;
  if (lane == 0) row_ptr[NN] = NE;
}

__global__ __launch_bounds__(1024) void scan_add(
    const int* __restrict__ bsum, int* __restrict__ row_ptr)
{
  int gid = blockIdx.x*1024 + threadIdx.x;
  if (gid < NN) row_ptr[gid] += bsum[blockIdx.x];
}

// bcur[b] = row_ptr[b*128]  (bucket write cursors for pair scatter)
__global__ __launch_bounds__(64) void bucket_init(const int* __restrict__ row_ptr, int* __restrict__ bcur)
{
  int b = blockIdx.x*64 + threadIdx.x;
  if (b < NB){
    int n = b*128; if (n > NN) n = NN;
    bcur[b] = row_ptr[n];
  }
}

// Pass A: scatter packed (src | local_dst<<17) into 128-node bucket regions.
// Appends to 391 hot tails -> L2 lines fully populated (no partial-line RMW storm).
__global__ __launch_bounds__(256) void fill_pairs(
    const int* __restrict__ src, const int* __restrict__ dst,
    int* bcur, uint* __restrict__ pairs)
{
  int e = blockIdx.x*256 + threadIdx.x;
  if (e < NE){
    int s = __builtin_nontemporal_load(&src[e]);
    int d = __builtin_nontemporal_load(&dst[e]);
    int b = d >> 7;
    int pos = atomicAdd(&bcur[b], 1);
    pairs[pos] = (uint)s | ((uint)(d & 127) << 17);
  }
}

// Pass B: per-bucket scatter into csr_src. Per-node cursors in LDS; writes confined
// to the bucket's contiguous ~8KB window -> fully-coalesced L2 lines.
__global__ __launch_bounds__(256) void fill_csr_bucket(
    const uint* __restrict__ pairs, const int* __restrict__ row_ptr,
    int* __restrict__ csr_src)
{
  __shared__ int lcur[128];
  int b = blockIdx.x;
  int n0 = b*128;
  int base = row_ptr[n0];
  int n1 = n0 + 128; if (n1 > NN) n1 = NN;
  int end = row_ptr[n1];
  int t = threadIdx.x;
  if (t < 128){
    int n = n0 + t;
    lcur[t] = ((n < NN) ? row_ptr[n] : end) - base;
  }
  __syncthreads();
  for (int p = base + t; p < end; p += 256){
    uint pk = pairs[p];
    int ld = pk >> 17;
    int pos = atomicAdd(&lcur[ld], 1);
    csr_src[base + pos] = (int)(pk & 0x1FFFFu);
  }
}

__global__ __launch_bounds__(64) void graph_ptr_kernel(const int* __restrict__ batch, int* __restrict__ gptr)
{
  int g = blockIdx.x*64 + threadIdx.x;
  if (g > NG) return;
  int lo = 0, hi = NN;
  while (lo < hi){
    int mid = (lo + hi) >> 1;
    if (batch[mid] < g) lo = mid + 1; else hi = mid;
  }
  gptr[g] = lo;
}

// ---------------- K2: sumh[n] = sum_{e: dst=n} h[src]  (bf16 in, bf16 out) ----------------
__global__ __launch_bounds__(256) void aggregate_bf16(
    const uint* __restrict__ m, const int* __restrict__ row_ptr,
    const int* __restrict__ csr_src, uint* __restrict__ aggr)
{
  int nid = blockIdx.x*4 + (threadIdx.x >> 6);
  int lane = threadIdx.x & 63;
  if (nid >= NN) return;
  int s0 = row_ptr[nid], s1 = row_ptr[nid+1];
  float ax = 0.f, ay = 0.f;
  int j = s0;
  for (; j + 7 < s1; j += 8){
    int si[8]; uint vv[8];
    #pragma unroll
    for (int q=0;q<8;q++) si[q] = csr_src[j+q];
    #pragma unroll
    for (int q=0;q<8;q++) vv[q] = m[(size_t)si[q]*64 + lane];
    #pragma unroll
    for (int q=0;q<8;q++){
      ax += __uint_as_float(vv[q] << 16);
      ay += __uint_as_float(vv[q] & 0xFFFF0000u);
    }
  }
  for (; j < s1; j++){
    int s = csr_src[j];
    uint v = m[(size_t)s*64 + lane];
    ax += __uint_as_float(v << 16);
    ay += __uint_as_float(v & 0xFFFF0000u);
  }
  aggr[(size_t)nid*64 + lane] = (uint)f2bf(ax) | ((uint)f2bf(ay) << 16);
}

// ---------------- K3: fused GRU via MFMA; 64 nodes/block, 4x weight reuse ----------------
__global__ __launch_bounds__(256, 2) void gru_mfma4(
    const ushort* __restrict__ sumh_bf, ushort* __restrict__ h_bf_out,
    const ushort* __restrict__ h_bf_in,
    const ushort* __restrict__ veffT, const ushort* __restrict__ whh_bf,
    const float* __restrict__ bs)
{
  __shared__ __align__(16) ushort lds_in[16384];       // 32 KB: 32 chunks of 1 KB
  __shared__ __align__(16) ushort lds_out[64*136];     // 17 KB hv bf16, stride 136
  int t = threadIdx.x;
  int wv = t >> 6, lane = t & 63;
  int mrow = lane & 15, quad = lane >> 4;
  int nb = blockIdx.x * 64;

  #pragma unroll
  for (int q = 0; q < 8; q++){
    int c = wv*8 + q;                      // c = arr*16 + tt*4 + kc
    int arr = c >> 4, tt = (c >> 2) & 3, kc = c & 3;
    const ushort* srcb = arr ? h_bf_in : sumh_bf;
    int node = nb + tt*16 + mrow; if (node >= NN) node = NN-1;
    uint4 v = *(const uint4*)&srcb[(size_t)node*HD + kc*32 + quad*8];
    *(uint4*)&lds_in[c*512 + lane*8] = v;
  }
  __syncthreads();

  floatx4 aR[4][2] = {}, aZ[4][2] = {}, aIN[4][2] = {}, aHN[4][2] = {};

  #pragma unroll
  for (int kc = 0; kc < 4; kc++){
    int k0 = kc*32 + quad*8;
    short8 fa[4], fh[4];
    #pragma unroll
    for (int tt = 0; tt < 4; tt++){
      fa[tt] = load_frag(&lds_in[((tt<<2) | kc)*512 + lane*8]);
      fh[tt] = load_frag(&lds_in[(16 | (tt<<2) | kc)*512 + lane*8]);
    }
    #pragma unroll
    for (int ftl = 0; ftl < 2; ftl++){
      size_t wo = (size_t)((wv*2 + ftl)*16 + mrow)*HD + k0;
      short8 vir = load_frag(&veffT[wo]);
      short8 viz = load_frag(&veffT[128*HD + wo]);
      short8 vin = load_frag(&veffT[256*HD + wo]);
      short8 whr = load_frag(&whh_bf[wo]);
      short8 whz = load_frag(&whh_bf[128*HD + wo]);
      short8 whn = load_frag(&whh_bf[256*HD + wo]);
      #pragma unroll
      for (int tt = 0; tt < 4; tt++){
        aR[tt][ftl]  = MFMA(fa[tt], vir, aR[tt][ftl]);
        aR[tt][ftl]  = MFMA(fh[tt], whr, aR[tt][ftl]);
        aZ[tt][ftl]  = MFMA(fa[tt], viz, aZ[tt][ftl]);
        aZ[tt][ftl]  = MFMA(fh[tt], whz, aZ[tt][ftl]);
        aIN[tt][ftl] = MFMA(fa[tt], vin, aIN[tt][ftl]);
        aHN[tt][ftl] = MFMA(fh[tt], whn, aHN[tt][ftl]);
      }
    }
  }

  #pragma unroll
  for (int ftl = 0; ftl < 2; ftl++){
    int feat = wv*32 + ftl*16 + mrow;
    float br  = bs[feat], bz = bs[128+feat], bin = bs[256+feat], bhn = bs[384+feat];
    int kw = ftl*16 + mrow;
    int qq = kw >> 3, jj = kw & 7;
    #pragma unroll
    for (int tt = 0; tt < 4; tt++){
      int cho = (16 | (tt<<2) | wv)*512;         // h chunk, kc = wv
      #pragma unroll
      for (int r = 0; r < 4; r++){
        int nrow = quad*4 + r;
        float rr = sigmf(aR[tt][ftl][r] + br);
        float zz = sigmf(aZ[tt][ftl][r] + bz);
        float nn = tanhff(aIN[tt][ftl][r] + bin + rr*(aHN[tt][ftl][r] + bhn));
        float ho = bf2f(lds_in[cho + (qq*16 + nrow)*8 + jj]);
        float hv = (1.f - zz)*nn + zz*ho;
        lds_out[(tt*16 + nrow)*136 + feat] = f2bf(hv);
      }
    }
  }
  __syncthreads();

  #pragma unroll
  for (int p = 0; p < 4; p++){
    int chunk = p*256 + t;
    int node = chunk >> 4, f = (chunk & 15)*8;
    int ng = nb + node;
    if (ng < NN){
      uint4 v = *(const uint4*)&lds_out[node*136 + f];
      *(uint4*)&h_bf_out[(size_t)ng*HD + f] = v;
    }
  }
}

// ---------------- local head: relu(hbf @ local_w^T + b) -> fp32 ----------------
__global__ __launch_bounds__(256) void local_gemm_mfma(
    const ushort* __restrict__ hbf, const ushort* __restrict__ lw_bf,
    const float* __restrict__ bias, float* __restrict__ local)
{
  int wv = threadIdx.x >> 6, lane = threadIdx.x & 63;
  int mt = blockIdx.x*4 + wv;
  if (mt >= NN/16) return;
  int m0 = mt*16, mrow = lane & 15, quad = lane >> 4;
  floatx4 acc[8] = {};
  for (int kc = 0; kc < 4; kc++){
    int k0 = kc*32 + quad*8;
    short8 a = load_frag(&hbf[(size_t)(m0 + mrow)*HD + k0]);
    #pragma unroll
    for (int ft = 0; ft < 8; ft++){
      short8 b = load_frag(&lw_bf[(size_t)(ft*16 + mrow)*HD + k0]);
      acc[ft] = MFMA(a, b, acc[ft]);
    }
  }
  #pragma unroll
  for (int ft = 0; ft < 8; ft++){
    float bv = bias[ft*16 + mrow];
    #pragma unroll
    for (int r = 0; r < 4; r++){
      int n = m0 + quad*4 + r;
      local[(size_t)n*HD + ft*16 + mrow] = fmaxf(acc[ft][r] + bv, 0.f);
    }
  }
}

// ---------------- segmented mean-pool (batch sorted, zero atomics) ----------------
__global__ __launch_bounds__(256) void pool_kernel(
    const float* __restrict__ local, const int* __restrict__ gptr,
    float* __restrict__ pooled)
{
  __shared__ float4 red[8][32];
  int g = blockIdx.x;
  int lane = threadIdx.x & 31;
  int st = threadIdx.x >> 5;
  int s0 = gptr[g], s1 = gptr[g+1];
  float4 acc = make_float4(0,0,0,0);
  for (int n = s0 + st; n < s1; n += 8){
    float4 v = *(const float4*)&local[(size_t)n*HD + lane*4];
    acc.x += v.x; acc.y += v.y; acc.z += v.z; acc.w += v.w;
  }
  red[st][lane] = acc;
  __syncthreads();
  if (st == 0){
    float4 s = red[0][lane];
    #pragma unroll
    for (int i=1;i<8;i++){
      float4 v = red[i][lane];
      s.x += v.x; s.y += v.y; s.z += v.z; s.w += v.w;
    }
    float cnt = (float)(s1 - s0);
    if (cnt < 1.0f) cnt = 1.0f;
    float inv = 1.0f / cnt;
    s.x *= inv; s.y *= inv; s.z *= inv; s.w *= inv;
    *(float4*)&pooled[g*HD + lane*4] = s;
  }
}

// ---------------- classifier + log_softmax ----------------
__global__ __launch_bounds__(64) void classifier_kernel(
    const float* __restrict__ pooled,
    const float* __restrict__ gw, const float* __restrict__ gb,
    float* __restrict__ out)
{
  int g = blockIdx.x;
  int lane = threadIdx.x;
  float p0 = pooled[g*HD + lane];
  float p1 = pooled[g*HD + 64 + lane];
  float vals[NC];
  #pragma unroll
  for (int c=0;c<NC;c++){
    float s = p0*gw[c*HD + lane] + p1*gw[c*HD + 64 + lane];
    #pragma unroll
    for (int off=32; off>0; off>>=1) s += __shfl_down(s, off, 64);
    vals[c] = s;
  }
  if (lane == 0){
    float mx = -1e30f;
    #pragma unroll
    for (int c=0;c<NC;c++){ vals[c] += gb[c]; mx = fmaxf(mx, vals[c]); }
    float se = 0.f;
    #pragma unroll
    for (int c=0;c<NC;c++) se += __expf(vals[c] - mx);
    float lse = mx + __logf(se);
    #pragma unroll
    for (int c=0;c<NC;c++) out[g*NC + c] = vals[c] - lse;
  }
}

extern "C" void kernel_launch(void* const* d_in, const int* in_sizes, int n_in,
                              void* d_out, int out_size, void* d_ws, size_t ws_size,
                              hipStream_t stream)
{
  const float* x        = (const float*)d_in[0];
  const int*   ei       = (const int*)  d_in[1];
  const int*   batch    = (const int*)  d_in[2];
  const float* W        = (const float*)d_in[3];
  const float* w_ih     = (const float*)d_in[4];
  const float* w_hh     = (const float*)d_in[5];
  const float* b_ih     = (const float*)d_in[6];
  const float* b_hh     = (const float*)d_in[7];
  const float* local_w  = (const float*)d_in[8];
  const float* local_b  = (const float*)d_in[9];
  const float* global_w = (const float*)d_in[10];
  const float* global_b = (const float*)d_in[11];
  float* out = (float*)d_out;

  // workspace layout
  char* base = (char*)d_ws;
  uint*   pairs   = (uint*)base;                      // 3.2 MB (first 25.6 MB region is free)
  int*    bcur    = (int*)(base + 3200000);           // NB ints
  char*   R       = base + 25600000;                  // 25.6 MB multi-use region
  ushort* sumh_bf = (ushort*)R;                       //   12.8 MB (live during layers)
  ushort* veffT   = (ushort*)(R + 12800000);          //   384 KB  (live during layers)
  ushort* whh_bf  = (ushort*)(R + 13193216);          //   96 KB   (live during layers)
  float*  bsums   = (float*)(R + 13291520);           //   2 KB    (live during layers)
  float*  local   = (float*)R;                        //   25.6 MB (after layers)
  ushort* xbf     = (ushort*)(base + 51200000);       // 12.8 MB
  ushort* hbf     = (ushort*)(base + 64000000);       // 12.8 MB
  ushort* lw_bf   = (ushort*)(base + 76800000);       // 32 KB
  float*  pooled  = (float*)(base + 76832768);        // 128 KB
  int* row_ptr    = (int*)(base + 76963840);          // NN+1
  int* deg        = row_ptr + (NN + 1);               // NN
  int* csr_src    = deg + NN;                         // NE
  int* gptr       = csr_src + NE;                     // NG+1
  int* bsum       = gptr + (NG + 1);                  // 49

  const int* esrc = ei;
  const int* edst = ei + NE;

  hipMemsetAsync(deg, 0, NN*sizeof(int), stream);
  prep_weights_bf16<<<259, 256, 0, stream>>>(w_hh, local_w, b_ih, b_hh, whh_bf, lw_bf, bsums);
  veff_kernel<<<768, 256, 0, stream>>>(W, w_ih, veffT);
  convert_x<<<6250, 256, 0, stream>>>((const float4*)x, (ushort4*)xbf);
  count_deg<<<3125, 256, 0, stream>>>(edst, deg);
  scan_blocks<<<49, 1024, 0, stream>>>(deg, row_ptr, bsum);
  scan_carry<<<1, 64, 0, stream>>>(bsum, row_ptr);
  scan_add<<<49, 1024, 0, stream>>>(bsum, row_ptr);
  bucket_init<<<7, 64, 0, stream>>>(row_ptr, bcur);
  fill_pairs<<<3125, 256, 0, stream>>>(esrc, edst, bcur, pairs);
  fill_csr_bucket<<<NB, 256, 0, stream>>>(pairs, row_ptr, csr_src);
  graph_ptr_kernel<<<5, 64, 0, stream>>>(batch, gptr);

  const ushort* hin_b = xbf;
  for (int l = 0; l < NL; l++){
    aggregate_bf16<<<12500, 256, 0, stream>>>((const uint*)hin_b, row_ptr, csr_src, (uint*)sumh_bf);
    gru_mfma4<<<782, 256, 0, stream>>>(sumh_bf, hbf, hin_b,
                                       veffT + (size_t)l*49152, whh_bf, bsums);
    hin_b = hbf;
  }

  local_gemm_mfma<<<782, 256, 0, stream>>>(hbf, lw_bf, local_b, local);
  pool_kernel<<<NG, 256, 0, stream>>>(local, gptr, pooled);
  classifier_kernel<<<NG, 64, 0, stream>>>(pooled, global_w, global_b, out);
}

// Round 9
// 559.883 us; speedup vs baseline: 1.4251x; 1.4251x over previous
//
#include <hip/hip_runtime.h>

#define NN 50000
#define NE 800000
#define HD 128
#define NL 4
#define NC 10
#define NG 256
#define NBK 12500         // CSR buckets of 4 nodes (NN = 4*NBK exactly)

typedef __attribute__((ext_vector_type(8))) short short8;    // 8 bf16 = 4 VGPR (MFMA A/B frag)
typedef __attribute__((ext_vector_type(4))) float floatx4;   // MFMA C/D frag

union frg { uint4 u; short8 s; };

__device__ __forceinline__ short8 load_frag(const ushort* p){
  frg f; f.u = *(const uint4*)p; return f.s;
}
__device__ __forceinline__ floatx4 MFMA(short8 a, short8 b, floatx4 c){
  return __builtin_amdgcn_mfma_f32_16x16x32_bf16(a, b, c, 0, 0, 0);
}

__device__ __forceinline__ ushort f2bf(float x){           // RNE fp32->bf16
  unsigned u = __float_as_uint(x);
  return (ushort)((u + 0x7FFFu + ((u >> 16) & 1u)) >> 16);
}
__device__ __forceinline__ float bf2f(ushort b){
  return __uint_as_float(((uint)b) << 16);
}
__device__ __forceinline__ float sigmf(float x){ return 1.0f/(1.0f + __expf(-x)); }
__device__ __forceinline__ float tanhff(float x){ return 2.0f/(1.0f + __expf(-2.0f*x)) - 1.0f; }

// ---------------- prep: convert whh / local_w to bf16; fold biases ----------------
__global__ __launch_bounds__(256) void prep_weights_bf16(
    const float* __restrict__ w_hh, const float* __restrict__ local_w,
    const float* __restrict__ b_ih, const float* __restrict__ b_hh,
    ushort* __restrict__ whh_bf, ushort* __restrict__ lw_bf,
    float* __restrict__ bs)
{
  int idx = blockIdx.x*256 + threadIdx.x;
  if (idx < 49152) whh_bf[idx] = f2bf(w_hh[idx]);
  else if (idx < 65536){ int j = idx - 49152; lw_bf[j] = f2bf(local_w[j]); }
  else if (idx < 66048){
    int j = idx - 65536;       // 0..511: br(128), bz(128), bin(128), bhn(128)
    if (j < 256)      bs[j] = b_ih[j] + b_hh[j];
    else if (j < 384) bs[j] = b_ih[j];          // bin
    else              bs[j] = b_hh[j - 128];    // bhn
  }
}

// ---------------- Veff[l]^T[o][j] = sum_f W[l][j][f] * wih[o][f]  (fp32 acc -> bf16) ----------------
__global__ __launch_bounds__(256) void veff_kernel(
    const float* __restrict__ W, const float* __restrict__ w_ih,
    ushort* __restrict__ veffT)
{
  int idx = blockIdx.x*256 + threadIdx.x;    // l*49152 + o*128 + j
  if (idx >= 4*49152) return;
  int l = idx / 49152, rem = idx % 49152;
  int o = rem >> 7, j = rem & 127;
  const float4* wr = (const float4*)&W[(size_t)(l*128 + j)*128];
  const float4* ir = (const float4*)&w_ih[(size_t)o*128];
  float acc = 0.f;
  #pragma unroll
  for (int q = 0; q < 32; q++){
    float4 a = wr[q], b = ir[q];
    acc += a.x*b.x + a.y*b.y + a.z*b.z + a.w*b.w;
  }
  veffT[idx] = f2bf(acc);
}

__global__ __launch_bounds__(256) void convert_x(const float4* __restrict__ x, ushort4* __restrict__ xbf)
{
  int i = blockIdx.x*256 + threadIdx.x;
  if (i < NN*HD/4){
    float4 v = x[i];
    ushort4 o; o.x=f2bf(v.x); o.y=f2bf(v.y); o.z=f2bf(v.z); o.w=f2bf(v.w);
    xbf[i] = o;
  }
}

// ---------------- CSR build ----------------
__global__ __launch_bounds__(256) void count_deg(const int* __restrict__ dst, int* deg)
{
  int e = blockIdx.x*256 + threadIdx.x;
  if (e < NE){
    int d = __builtin_nontemporal_load(&dst[e]);
    atomicAdd(&deg[d], 1);
  }
}

__global__ __launch_bounds__(1024) void scan_blocks(
    const int* __restrict__ deg, int* __restrict__ excl_out, int* __restrict__ bsum)
{
  __shared__ int wsum[16];
  int t = threadIdx.x;
  int gid = blockIdx.x*1024 + t;
  int v = (gid < NN) ? deg[gid] : 0;
  int lane = t & 63, wv = t >> 6;
  int incl = v;
  #pragma unroll
  for (int off=1; off<64; off<<=1){
    int y = __shfl_up(incl, off, 64);
    if (lane >= off) incl += y;
  }
  if (lane == 63) wsum[wv] = incl;
  __syncthreads();
  if (wv == 0){
    int s = (lane < 16) ? wsum[lane] : 0;
    #pragma unroll
    for (int off=1; off<16; off<<=1){
      int y = __shfl_up(s, off, 64);
      if (lane >= off) s += y;
    }
    if (lane < 16) wsum[lane] = s;
  }
  __syncthreads();
  int wpre = (wv > 0) ? wsum[wv-1] : 0;
  if (gid < NN) excl_out[gid] = wpre + incl - v;
  if (t == 1023) bsum[blockIdx.x] = wpre + incl;
}

__global__ __launch_bounds__(64) void scan_carry(int* bsum, int* __restrict__ row_ptr)
{
  int lane = threadIdx.x;
  int v = (lane < 49) ? bsum[lane] : 0;
  int incl = v;
  #pragma unroll
  for (int off=1; off<64; off<<=1){
    int y = __shfl_up(incl, off, 64);
    if (lane >= off) incl += y;
  }
  if (lane < 49) bsum[lane] = incl - v;
  if (lane == 0) row_ptr[NN] = NE;
}

__global__ __launch_bounds__(1024) void scan_add(
    const int* __restrict__ bsum, int* __restrict__ row_ptr)
{
  int gid = blockIdx.x*1024 + threadIdx.x;
  if (gid < NN) row_ptr[gid] += bsum[blockIdx.x];
}

// bcur[b] = row_ptr[b*4]  (bucket write cursors for pair scatter)
__global__ __launch_bounds__(256) void bucket_init(const int* __restrict__ row_ptr, int* __restrict__ bcur)
{
  int b = blockIdx.x*256 + threadIdx.x;
  if (b < NBK) bcur[b] = row_ptr[b*4];
}

// Pass A: scatter packed (src | local_dst<<17) into 4-node bucket regions.
// 12500 tails: atomic chains ~64 deep (round-8 lesson: 391 tails -> 2046-deep chains
// serialized at ~330cyc each = 281us; 64-deep floor is ~9us), writes stay line-dense.
__global__ __launch_bounds__(256) void fill_pairs(
    const int* __restrict__ src, const int* __restrict__ dst,
    int* bcur, uint* __restrict__ pairs)
{
  int e = blockIdx.x*256 + threadIdx.x;
  if (e < NE){
    int s = __builtin_nontemporal_load(&src[e]);
    int d = __builtin_nontemporal_load(&dst[e]);
    int b = d >> 2;
    int pos = atomicAdd(&bcur[b], 1);
    pairs[pos] = (uint)s | ((uint)(d & 3) << 17);
  }
}

// Pass B: one wave per bucket; 4 per-node cursors in LDS; scatter confined to the
// bucket's ~256B contiguous csr window -> fully-coalesced L2 lines.
__global__ __launch_bounds__(64) void fill_csr_bucket(
    const uint* __restrict__ pairs, const int* __restrict__ row_ptr,
    int* __restrict__ csr_src)
{
  __shared__ int lcur[4];
  int b = blockIdx.x;
  int n0 = b*4;
  int base = row_ptr[n0];
  int end  = row_ptr[n0+4];
  int t = threadIdx.x;
  if (t < 4) lcur[t] = row_ptr[n0 + t] - base;
  __syncthreads();
  for (int p = base + t; p < end; p += 64){
    uint pk = pairs[p];
    int ld = pk >> 17;
    int pos = atomicAdd(&lcur[ld], 1);
    csr_src[base + pos] = (int)(pk & 0x1FFFFu);
  }
}

__global__ __launch_bounds__(64) void graph_ptr_kernel(const int* __restrict__ batch, int* __restrict__ gptr)
{
  int g = blockIdx.x*64 + threadIdx.x;
  if (g > NG) return;
  int lo = 0, hi = NN;
  while (lo < hi){
    int mid = (lo + hi) >> 1;
    if (batch[mid] < g) lo = mid + 1; else hi = mid;
  }
  gptr[g] = lo;
}

// ---------------- K2: sumh[n] = sum_{e: dst=n} h[src]  (bf16 in, bf16 out) ----------------
__global__ __launch_bounds__(256) void aggregate_bf16(
    const uint* __restrict__ m, const int* __restrict__ row_ptr,
    const int* __restrict__ csr_src, uint* __restrict__ aggr)
{
  int nid = blockIdx.x*4 + (threadIdx.x >> 6);
  int lane = threadIdx.x & 63;
  if (nid >= NN) return;
  int s0 = row_ptr[nid], s1 = row_ptr[nid+1];
  float ax = 0.f, ay = 0.f;
  int j = s0;
  for (; j + 7 < s1; j += 8){
    int si[8]; uint vv[8];
    #pragma unroll
    for (int q=0;q<8;q++) si[q] = csr_src[j+q];
    #pragma unroll
    for (int q=0;q<8;q++) vv[q] = m[(size_t)si[q]*64 + lane];
    #pragma unroll
    for (int q=0;q<8;q++){
      ax += __uint_as_float(vv[q] << 16);
      ay += __uint_as_float(vv[q] & 0xFFFF0000u);
    }
  }
  for (; j < s1; j++){
    int s = csr_src[j];
    uint v = m[(size_t)s*64 + lane];
    ax += __uint_as_float(v << 16);
    ay += __uint_as_float(v & 0xFFFF0000u);
  }
  aggr[(size_t)nid*64 + lane] = (uint)f2bf(ax) | ((uint)f2bf(ay) << 16);
}

// ---------------- K3: fused GRU via MFMA; 64 nodes/block, 4x weight reuse ----------------
__global__ __launch_bounds__(256, 2) void gru_mfma4(
    const ushort* __restrict__ sumh_bf, ushort* __restrict__ h_bf_out,
    const ushort* __restrict__ h_bf_in,
    const ushort* __restrict__ veffT, const ushort* __restrict__ whh_bf,
    const float* __restrict__ bs)
{
  __shared__ __align__(16) ushort lds_in[16384];       // 32 KB: 32 chunks of 1 KB
  __shared__ __align__(16) ushort lds_out[64*136];     // 17 KB hv bf16, stride 136
  int t = threadIdx.x;
  int wv = t >> 6, lane = t & 63;
  int mrow = lane & 15, quad = lane >> 4;
  int nb = blockIdx.x * 64;

  #pragma unroll
  for (int q = 0; q < 8; q++){
    int c = wv*8 + q;                      // c = arr*16 + tt*4 + kc
    int arr = c >> 4, tt = (c >> 2) & 3, kc = c & 3;
    const ushort* srcb = arr ? h_bf_in : sumh_bf;
    int node = nb + tt*16 + mrow; if (node >= NN) node = NN-1;
    uint4 v = *(const uint4*)&srcb[(size_t)node*HD + kc*32 + quad*8];
    *(uint4*)&lds_in[c*512 + lane*8] = v;
  }
  __syncthreads();

  floatx4 aR[4][2] = {}, aZ[4][2] = {}, aIN[4][2] = {}, aHN[4][2] = {};

  #pragma unroll
  for (int kc = 0; kc < 4; kc++){
    int k0 = kc*32 + quad*8;
    short8 fa[4], fh[4];
    #pragma unroll
    for (int tt = 0; tt < 4; tt++){
      fa[tt] = load_frag(&lds_in[((tt<<2) | kc)*512 + lane*8]);
      fh[tt] = load_frag(&lds_in[(16 | (tt<<2) | kc)*512 + lane*8]);
    }
    #pragma unroll
    for (int ftl = 0; ftl < 2; ftl++){
      size_t wo = (size_t)((wv*2 + ftl)*16 + mrow)*HD + k0;
      short8 vir = load_frag(&veffT[wo]);
      short8 viz = load_frag(&veffT[128*HD + wo]);
      short8 vin = load_frag(&veffT[256*HD + wo]);
      short8 whr = load_frag(&whh_bf[wo]);
      short8 whz = load_frag(&whh_bf[128*HD + wo]);
      short8 whn = load_frag(&whh_bf[256*HD + wo]);
      #pragma unroll
      for (int tt = 0; tt < 4; tt++){
        aR[tt][ftl]  = MFMA(fa[tt], vir, aR[tt][ftl]);
        aR[tt][ftl]  = MFMA(fh[tt], whr, aR[tt][ftl]);
        aZ[tt][ftl]  = MFMA(fa[tt], viz, aZ[tt][ftl]);
        aZ[tt][ftl]  = MFMA(fh[tt], whz, aZ[tt][ftl]);
        aIN[tt][ftl] = MFMA(fa[tt], vin, aIN[tt][ftl]);
        aHN[tt][ftl] = MFMA(fh[tt], whn, aHN[tt][ftl]);
      }
    }
  }

  #pragma unroll
  for (int ftl = 0; ftl < 2; ftl++){
    int feat = wv*32 + ftl*16 + mrow;
    float br  = bs[feat], bz = bs[128+feat], bin = bs[256+feat], bhn = bs[384+feat];
    int kw = ftl*16 + mrow;
    int qq = kw >> 3, jj = kw & 7;
    #pragma unroll
    for (int tt = 0; tt < 4; tt++){
      int cho = (16 | (tt<<2) | wv)*512;         // h chunk, kc = wv
      #pragma unroll
      for (int r = 0; r < 4; r++){
        int nrow = quad*4 + r;
        float rr = sigmf(aR[tt][ftl][r] + br);
        float zz = sigmf(aZ[tt][ftl][r] + bz);
        float nn = tanhff(aIN[tt][ftl][r] + bin + rr*(aHN[tt][ftl][r] + bhn));
        float ho = bf2f(lds_in[cho + (qq*16 + nrow)*8 + jj]);
        float hv = (1.f - zz)*nn + zz*ho;
        lds_out[(tt*16 + nrow)*136 + feat] = f2bf(hv);
      }
    }
  }
  __syncthreads();

  #pragma unroll
  for (int p = 0; p < 4; p++){
    int chunk = p*256 + t;
    int node = chunk >> 4, f = (chunk & 15)*8;
    int ng = nb + node;
    if (ng < NN){
      uint4 v = *(const uint4*)&lds_out[node*136 + f];
      *(uint4*)&h_bf_out[(size_t)ng*HD + f] = v;
    }
  }
}

// ---------------- local head: relu(hbf @ local_w^T + b) -> fp32 ----------------
__global__ __launch_bounds__(256) void local_gemm_mfma(
    const ushort* __restrict__ hbf, const ushort* __restrict__ lw_bf,
    const float* __restrict__ bias, float* __restrict__ local)
{
  int wv = threadIdx.x >> 6, lane = threadIdx.x & 63;
  int mt = blockIdx.x*4 + wv;
  if (mt >= NN/16) return;
  int m0 = mt*16, mrow = lane & 15, quad = lane >> 4;
  floatx4 acc[8] = {};
  for (int kc = 0; kc < 4; kc++){
    int k0 = kc*32 + quad*8;
    short8 a = load_frag(&hbf[(size_t)(m0 + mrow)*HD + k0]);
    #pragma unroll
    for (int ft = 0; ft < 8; ft++){
      short8 b = load_frag(&lw_bf[(size_t)(ft*16 + mrow)*HD + k0]);
      acc[ft] = MFMA(a, b, acc[ft]);
    }
  }
  #pragma unroll
  for (int ft = 0; ft < 8; ft++){
    float bv = bias[ft*16 + mrow];
    #pragma unroll
    for (int r = 0; r < 4; r++){
      int n = m0 + quad*4 + r;
      local[(size_t)n*HD + ft*16 + mrow] = fmaxf(acc[ft][r] + bv, 0.f);
    }
  }
}

// ---------------- segmented mean-pool (batch sorted, zero atomics) ----------------
__global__ __launch_bounds__(256) void pool_kernel(
    const float* __restrict__ local, const int* __restrict__ gptr,
    float* __restrict__ pooled)
{
  __shared__ float4 red[8][32];
  int g = blockIdx.x;
  int lane = threadIdx.x & 31;
  int st = threadIdx.x >> 5;
  int s0 = gptr[g], s1 = gptr[g+1];
  float4 acc = make_float4(0,0,0,0);
  for (int n = s0 + st; n < s1; n += 8){
    float4 v = *(const float4*)&local[(size_t)n*HD + lane*4];
    acc.x += v.x; acc.y += v.y; acc.z += v.z; acc.w += v.w;
  }
  red[st][lane] = acc;
  __syncthreads();
  if (st == 0){
    float4 s = red[0][lane];
    #pragma unroll
    for (int i=1;i<8;i++){
      float4 v = red[i][lane];
      s.x += v.x; s.y += v.y; s.z += v.z; s.w += v.w;
    }
    float cnt = (float)(s1 - s0);
    if (cnt < 1.0f) cnt = 1.0f;
    float inv = 1.0f / cnt;
    s.x *= inv; s.y *= inv; s.z *= inv; s.w *= inv;
    *(float4*)&pooled[g*HD + lane*4] = s;
  }
}

// ---------------- classifier + log_softmax ----------------
__global__ __launch_bounds__(64) void classifier_kernel(
    const float* __restrict__ pooled,
    const float* __restrict__ gw, const float* __restrict__ gb,
    float* __restrict__ out)
{
  int g = blockIdx.x;
  int lane = threadIdx.x;
  float p0 = pooled[g*HD + lane];
  float p1 = pooled[g*HD + 64 + lane];
  float vals[NC];
  #pragma unroll
  for (int c=0;c<NC;c++){
    float s = p0*gw[c*HD + lane] + p1*gw[c*HD + 64 + lane];
    #pragma unroll
    for (int off=32; off>0; off>>=1) s += __shfl_down(s, off, 64);
    vals[c] = s;
  }
  if (lane == 0){
    float mx = -1e30f;
    #pragma unroll
    for (int c=0;c<NC;c++){ vals[c] += gb[c]; mx = fmaxf(mx, vals[c]); }
    float se = 0.f;
    #pragma unroll
    for (int c=0;c<NC;c++) se += __expf(vals[c] - mx);
    float lse = mx + __logf(se);
    #pragma unroll
    for (int c=0;c<NC;c++) out[g*NC + c] = vals[c] - lse;
  }
}

extern "C" void kernel_launch(void* const* d_in, const int* in_sizes, int n_in,
                              void* d_out, int out_size, void* d_ws, size_t ws_size,
                              hipStream_t stream)
{
  const float* x        = (const float*)d_in[0];
  const int*   ei       = (const int*)  d_in[1];
  const int*   batch    = (const int*)  d_in[2];
  const float* W        = (const float*)d_in[3];
  const float* w_ih     = (const float*)d_in[4];
  const float* w_hh     = (const float*)d_in[5];
  const float* b_ih     = (const float*)d_in[6];
  const float* b_hh     = (const float*)d_in[7];
  const float* local_w  = (const float*)d_in[8];
  const float* local_b  = (const float*)d_in[9];
  const float* global_w = (const float*)d_in[10];
  const float* global_b = (const float*)d_in[11];
  float* out = (float*)d_out;

  // workspace layout
  char* base = (char*)d_ws;
  uint*   pairs   = (uint*)base;                      // 3.2 MB (first 25.6 MB region is free)
  int*    bcur    = (int*)(base + 3200000);           // NBK ints (50 KB)
  char*   R       = base + 25600000;                  // 25.6 MB multi-use region
  ushort* sumh_bf = (ushort*)R;                       //   12.8 MB (live during layers)
  ushort* veffT   = (ushort*)(R + 12800000);          //   384 KB  (live during layers)
  ushort* whh_bf  = (ushort*)(R + 13193216);          //   96 KB   (live during layers)
  float*  bsums   = (float*)(R + 13291520);           //   2 KB    (live during layers)
  float*  local   = (float*)R;                        //   25.6 MB (after layers)
  ushort* xbf     = (ushort*)(base + 51200000);       // 12.8 MB
  ushort* hbf     = (ushort*)(base + 64000000);       // 12.8 MB
  ushort* lw_bf   = (ushort*)(base + 76800000);       // 32 KB
  float*  pooled  = (float*)(base + 76832768);        // 128 KB
  int* row_ptr    = (int*)(base + 76963840);          // NN+1
  int* deg        = row_ptr + (NN + 1);               // NN
  int* csr_src    = deg + NN;                         // NE
  int* gptr       = csr_src + NE;                     // NG+1
  int* bsum       = gptr + (NG + 1);                  // 49

  const int* esrc = ei;
  const int* edst = ei + NE;

  hipMemsetAsync(deg, 0, NN*sizeof(int), stream);
  prep_weights_bf16<<<259, 256, 0, stream>>>(w_hh, local_w, b_ih, b_hh, whh_bf, lw_bf, bsums);
  veff_kernel<<<768, 256, 0, stream>>>(W, w_ih, veffT);
  convert_x<<<6250, 256, 0, stream>>>((const float4*)x, (ushort4*)xbf);
  count_deg<<<3125, 256, 0, stream>>>(edst, deg);
  scan_blocks<<<49, 1024, 0, stream>>>(deg, row_ptr, bsum);
  scan_carry<<<1, 64, 0, stream>>>(bsum, row_ptr);
  scan_add<<<49, 1024, 0, stream>>>(bsum, row_ptr);
  bucket_init<<<49, 256, 0, stream>>>(row_ptr, bcur);
  fill_pairs<<<3125, 256, 0, stream>>>(esrc, edst, bcur, pairs);
  fill_csr_bucket<<<NBK, 64, 0, stream>>>(pairs, row_ptr, csr_src);
  graph_ptr_kernel<<<5, 64, 0, stream>>>(batch, gptr);

  const ushort* hin_b = xbf;
  for (int l = 0; l < NL; l++){
    aggregate_bf16<<<12500, 256, 0, stream>>>((const uint*)hin_b, row_ptr, csr_src, (uint*)sumh_bf);
    gru_mfma4<<<782, 256, 0, stream>>>(sumh_bf, hbf, hin_b,
                                       veffT + (size_t)l*49152, whh_bf, bsums);
    hin_b = hbf;
  }

  local_gemm_mfma<<<782, 256, 0, stream>>>(hbf, lw_bf, local_b, local);
  pool_kernel<<<NG, 256, 0, stream>>>(local, gptr, pooled);
  classifier_kernel<<<NG, 64, 0, stream>>>(pooled, global_w, global_b, out);
}